// Round 3
// baseline (7076.327 us; speedup 1.0000x reference)
//
#include <hip/hip_runtime.h>
#include <hip/hip_bf16.h>
#include <math.h>

// Problem constants
#define Bn   16
#define Dn   64
#define Tn   3000
#define Nn   (Bn*Tn)          // 48000
#define NCB  8
#define Kn   1024
#define KCH  64               // codes staged in LDS per chunk
#define NCHK (Kn/KCH)         // 16

// Workspace byte offsets
#define WS_RES  0                              // float[3072000] residual
#define WS_SE   12288000                       // float[NCB*Kn]
#define WS_USED (WS_SE + NCB*Kn*4)             // float[NCB*Kn]
#define WS_LOSS (WS_USED + NCB*Kn*4)           // float[1] (+pad)
#define WS_END  (WS_LOSS + 16)

// Output element offsets (fp32 elements!)
#define OUT_QT_OFF  0
#define OUT_IDX_OFF 3072000
#define OUT_SC_OFF  3456000

// ---------- precompute ||e_k||^2 for all 8 codebooks ----------
__global__ void vq_se(const float* __restrict__ emb, float* __restrict__ se)
{
    int r = blockIdx.x * 256 + threadIdx.x;   // 0..8191
    if (r < NCB*Kn) {
        const float* p = emb + r*Dn;
        float a0=0.f, a1=0.f, a2=0.f, a3=0.f;
        #pragma unroll
        for (int d = 0; d < Dn; d += 4) {
            a0 = fmaf(p[d+0], p[d+0], a0);
            a1 = fmaf(p[d+1], p[d+1], a1);
            a2 = fmaf(p[d+2], p[d+2], a2);
            a3 = fmaf(p[d+3], p[d+3], a3);
        }
        se[r] = (a0+a1)+(a2+a3);
    }
}

// ---------- fused per-stage: distances + argmin + residual update ----------
// grid 188, block 256, one residual vector per thread kept in registers.
__global__ void vq_stage(float* __restrict__ res, const float* __restrict__ emb,
                         const float* __restrict__ se,
                         float* __restrict__ out_idx,             // + stage*Nn (fp32)
                         float* __restrict__ used,                // + stage*Kn
                         float* __restrict__ loss_acc)
{
    __shared__ __align__(16) float elds[KCH*Dn];   // 16 KB codebook chunk
    __shared__ float selds[KCH];
    __shared__ float red[256];
    const int tid = threadIdx.x;
    const int n = blockIdx.x * 256 + tid;
    const bool valid = (n < Nn);
    const int nn = valid ? n : 0;
    const int b = nn / Tn, t = nn % Tn;
    float* rp = res + b*(Dn*Tn) + t;

    // residual vector -> registers; ||r||^2 (fp32, 4 chains)
    float4 r[16];
    #pragma unroll
    for (int dd = 0; dd < 16; ++dd) {
        float4 a;
        a.x = rp[(4*dd+0)*Tn]; a.y = rp[(4*dd+1)*Tn];
        a.z = rp[(4*dd+2)*Tn]; a.w = rp[(4*dd+3)*Tn];
        r[dd] = a;
    }
    float a0=0.f,a1=0.f,a2=0.f,a3=0.f;
    #pragma unroll
    for (int dd = 0; dd < 16; ++dd) {
        a0 = fmaf(r[dd].x, r[dd].x, a0);
        a1 = fmaf(r[dd].y, r[dd].y, a1);
        a2 = fmaf(r[dd].z, r[dd].z, a2);
        a3 = fmaf(r[dd].w, r[dd].w, a3);
    }
    const float sr = (a0+a1)+(a2+a3);

    float best = INFINITY;
    int bk = 0;
    for (int c = 0; c < NCHK; ++c) {
        const int kbase = c * KCH;
        __syncthreads();                        // elds safe to overwrite
        {
            const float4* src = (const float4*)(emb + kbase*Dn);
            float4* dst = (float4*)elds;
            #pragma unroll
            for (int j = 0; j < (KCH*Dn/4)/256; ++j)   // 4 float4 per thread
                dst[tid + j*256] = src[tid + j*256];
            if (tid < KCH) selds[tid] = se[kbase + tid];
        }
        __syncthreads();
        #pragma unroll 4
        for (int k = 0; k < KCH; ++k) {
            float q0=0.f,q1=0.f,q2=0.f,q3=0.f;
            #pragma unroll
            for (int dd = 0; dd < 16; ++dd) {
                float4 e4 = ((const float4*)elds)[k*16 + dd];
                q0 = fmaf(r[dd].x, e4.x, q0);
                q1 = fmaf(r[dd].y, e4.y, q1);
                q2 = fmaf(r[dd].z, e4.z, q2);
                q3 = fmaf(r[dd].w, e4.w, q3);
            }
            float dot = (q0+q1)+(q2+q3);
            // mirror reference rounding order: (s_r - 2*dot) + s_e, all fp32
            float d2 = (sr - 2.0f*dot) + selds[k];
            int kg = kbase + k;
            if (d2 < best) { best = d2; bk = kg; }   // strict <: np first-occurrence tie-break
        }
    }

    float lsum = 0.f;
    if (valid) {
        bk &= (Kn - 1);                          // provably no-op OOB guard
        out_idx[n] = (float)bk;                  // fp32 index output
        used[bk] = 1.0f;
        const float* ep = emb + bk*Dn;
        #pragma unroll
        for (int dd = 0; dd < 16; ++dd) {
            float rv4[4] = { r[dd].x, r[dd].y, r[dd].z, r[dd].w };
            #pragma unroll
            for (int j = 0; j < 4; ++j) {
                int d = 4*dd + j;
                float rv = rv4[j];
                float q  = ep[d];
                float diff = rv - q;             // loss uses raw q
                lsum = fmaf(diff, diff, lsum);
                float qst = rv + (q - rv);       // straight-through, fp32-faithful
                rp[d*Tn] = rv - qst;
            }
        }
    }
    red[tid] = lsum;
    __syncthreads();
    for (int s2 = 128; s2 > 0; s2 >>= 1) {
        if (tid < s2) red[tid] += red[tid + s2];
        __syncthreads();
    }
    if (tid == 0) atomicAdd(loss_acc, red[0]);
}

// ---------- quantized_total = x - residual_final (fp32 out) ----------
__global__ void vq_qt(const float* __restrict__ x, const float* __restrict__ res,
                      float* __restrict__ out)
{
    int j = blockIdx.x * 256 + threadIdx.x;   // float4 units: 768000
    if (j < (Nn*Dn)/4) {
        float4 xv = ((const float4*)x)[j];
        float4 rv = ((const float4*)res)[j];
        float4 o;
        o.x = xv.x - rv.x;
        o.y = xv.y - rv.y;
        o.z = xv.z - rv.z;
        o.w = xv.w - rv.w;
        ((float4*)out)[j] = o;
    }
}

// ---------- scalars: (commit+codebook)/NCB and utilization (fp32 out) ----------
__global__ void vq_scalars(const float* __restrict__ used, const float* __restrict__ loss_acc,
                           float* __restrict__ out)
{
    __shared__ float red[256];
    float s = 0.f;
    for (int j = threadIdx.x; j < NCB*Kn; j += 256) s += used[j];
    red[threadIdx.x] = s;
    __syncthreads();
    for (int st = 128; st > 0; st >>= 1) {
        if (threadIdx.x < st) red[threadIdx.x] += red[threadIdx.x + st];
        __syncthreads();
    }
    if (threadIdx.x == 0) {
        float sumsq = loss_acc[0];
        float total_loss = 2.0f * sumsq / (float)(Nn*Dn);  // sum over stages of commit+codebook
        out[OUT_SC_OFF + 0] = total_loss / (float)NCB;
        out[OUT_SC_OFF + 1] = red[0] / (float)(NCB*Kn);
    }
}

extern "C" void kernel_launch(void* const* d_in, const int* in_sizes, int n_in,
                              void* d_out, int out_size, void* d_ws, size_t ws_size,
                              hipStream_t stream)
{
    const float* x      = (const float*)d_in[0];
    const float* embeds = (const float*)d_in[1];
    float* out = (float*)d_out;
    char* ws = (char*)d_ws;

    float* res  = (float*)(ws + WS_RES);
    float* se   = (float*)(ws + WS_SE);
    float* used = (float*)(ws + WS_USED);
    float* loss = (float*)(ws + WS_LOSS);

    // init: residual = x; used/loss = 0
    hipMemcpyAsync(res, x, (size_t)Nn*Dn*sizeof(float), hipMemcpyDeviceToDevice, stream);
    hipMemsetAsync(used, 0, (size_t)NCB*Kn*sizeof(float) + 16, stream);

    vq_se<<<(NCB*Kn + 255)/256, 256, 0, stream>>>(embeds, se);

    for (int s = 0; s < NCB; ++s) {
        const float* emb_s = embeds + (size_t)s*Kn*Dn;
        vq_stage<<<(Nn + 255)/256, 256, 0, stream>>>(res, emb_s, se + s*Kn,
                                                     out + OUT_IDX_OFF + s*Nn,
                                                     used + s*Kn, loss);
    }

    vq_qt<<<((Nn*Dn)/4 + 255)/256, 256, 0, stream>>>(x, res, out + OUT_QT_OFF);
    vq_scalars<<<1, 256, 0, stream>>>(used, loss, out);
}

// Round 4
// 1250.584 us; speedup vs baseline: 5.6584x; 5.6584x over previous
//
#include <hip/hip_runtime.h>
#include <hip/hip_bf16.h>
#include <math.h>

// Problem constants
#define Bn   16
#define Dn   64
#define Tn   3000
#define Nn   (Bn*Tn)          // 48000
#define NCB  8
#define Kn   1024
#define KCH  64               // codes per k-chunk (LDS staged)
#define KSPL (Kn/KCH)         // 16 k-chunks
#define NTIL ((Nn + 255)/256) // 188 n-tiles
#define PSTR 48128            // padded partial stride (>= Nn, 128-aligned)

// Workspace byte offsets
#define WS_RES  0                              // float[3072000] residual
#define WS_PVAL 12288000                       // float[KSPL*PSTR]
#define WS_PIDX (WS_PVAL + KSPL*PSTR*4)        // int[KSPL*PSTR]
#define WS_SE   (WS_PIDX + KSPL*PSTR*4)        // float[NCB*Kn]
#define WS_USED (WS_SE + NCB*Kn*4)             // float[NCB*Kn]
#define WS_LOSS (WS_USED + NCB*Kn*4)           // float[1] (+pad)
#define WS_END  (WS_LOSS + 16)

// Output element offsets (fp32 elements)
#define OUT_QT_OFF  0
#define OUT_IDX_OFF 3072000
#define OUT_SC_OFF  3456000

// ---------- precompute ||e_k||^2 for all 8 codebooks ----------
__global__ void vq_se(const float* __restrict__ emb, float* __restrict__ se)
{
    int r = blockIdx.x * 256 + threadIdx.x;   // 0..8191
    if (r < NCB*Kn) {
        const float* p = emb + r*Dn;
        float a0=0.f, a1=0.f, a2=0.f, a3=0.f;
        #pragma unroll
        for (int d = 0; d < Dn; d += 4) {
            a0 = fmaf(p[d+0], p[d+0], a0);
            a1 = fmaf(p[d+1], p[d+1], a1);
            a2 = fmaf(p[d+2], p[d+2], a2);
            a3 = fmaf(p[d+3], p[d+3], a3);
        }
        se[r] = (a0+a1)+(a2+a3);
    }
}

// ---------- distance + per-chunk argmin ----------
// grid (NTIL, KSPL), block 256, 1 residual vector per thread in registers.
// Arithmetic chains bit-identical to the verified round-3 kernel.
__global__ __launch_bounds__(256, 4)
void vq_dist(const float* __restrict__ res, const float* __restrict__ emb,
             const float* __restrict__ se,
             float* __restrict__ pval, int* __restrict__ pidx)
{
    __shared__ __align__(16) float elds[KCH*Dn];   // 16 KB codebook chunk
    __shared__ float selds[KCH];
    const int tid = threadIdx.x;
    const int kch = blockIdx.y;
    const int kbase = kch * KCH;
    const int n = blockIdx.x * 256 + tid;
    const bool valid = (n < Nn);
    const int nn = valid ? n : 0;
    const int b = nn / Tn, t = nn % Tn;
    const float* rp = res + b*(Dn*Tn) + t;

    // stage codebook chunk [KCH][64] into LDS (coalesced float4 copy)
    {
        const float4* src = (const float4*)(emb + kbase*Dn);
        float4* dst = (float4*)elds;
        #pragma unroll
        for (int j = 0; j < (KCH*Dn/4)/256; ++j)   // 4 float4 per thread
            dst[tid + j*256] = src[tid + j*256];
        if (tid < KCH) selds[tid] = se[kbase + tid];
    }

    // residual vector -> registers; ||r||^2 (fp32, 4 chains) — identical to round 3
    float4 r[16];
    #pragma unroll
    for (int dd = 0; dd < 16; ++dd) {
        float4 a;
        a.x = rp[(4*dd+0)*Tn]; a.y = rp[(4*dd+1)*Tn];
        a.z = rp[(4*dd+2)*Tn]; a.w = rp[(4*dd+3)*Tn];
        r[dd] = a;
    }
    float a0=0.f,a1=0.f,a2=0.f,a3=0.f;
    #pragma unroll
    for (int dd = 0; dd < 16; ++dd) {
        a0 = fmaf(r[dd].x, r[dd].x, a0);
        a1 = fmaf(r[dd].y, r[dd].y, a1);
        a2 = fmaf(r[dd].z, r[dd].z, a2);
        a3 = fmaf(r[dd].w, r[dd].w, a3);
    }
    const float sr = (a0+a1)+(a2+a3);

    __syncthreads();

    float best = INFINITY;
    int bk = 0;
    #pragma unroll 4
    for (int k = 0; k < KCH; ++k) {
        float q0=0.f,q1=0.f,q2=0.f,q3=0.f;
        #pragma unroll
        for (int dd = 0; dd < 16; ++dd) {
            float4 e4 = ((const float4*)elds)[k*16 + dd];
            q0 = fmaf(r[dd].x, e4.x, q0);
            q1 = fmaf(r[dd].y, e4.y, q1);
            q2 = fmaf(r[dd].z, e4.z, q2);
            q3 = fmaf(r[dd].w, e4.w, q3);
        }
        float dot = (q0+q1)+(q2+q3);
        // mirror reference rounding order: (s_r - 2*dot) + s_e, all fp32
        float d2 = (sr - 2.0f*dot) + selds[k];
        int kg = kbase + k;
        if (d2 < best) { best = d2; bk = kg; }   // strict <: first-occurrence tie-break
    }
    if (valid) { pval[kch*PSTR + n] = best; pidx[kch*PSTR + n] = bk; }
}

// ---------- combine partials + residual update + loss/util ----------
__global__ void vq_comb(float* __restrict__ res, const float* __restrict__ emb,
                        const float* __restrict__ pval, const int* __restrict__ pidx,
                        float* __restrict__ out_idx,             // + stage*Nn (fp32)
                        float* __restrict__ used,                // + stage*Kn
                        float* __restrict__ loss_acc)
{
    __shared__ float red[256];
    const int tid = threadIdx.x;
    const int n = blockIdx.x * 256 + tid;
    float lsum = 0.f;
    if (n < Nn) {
        float best = INFINITY; int bk = 0;
        #pragma unroll
        for (int c = 0; c < KSPL; ++c) {          // ascending chunks: global first-occurrence
            float v = pval[c*PSTR + n];
            int   k = pidx[c*PSTR + n];
            if (v < best) { best = v; bk = k; }
        }
        bk &= (Kn - 1);                           // provably no-op OOB guard
        out_idx[n] = (float)bk;
        used[bk] = 1.0f;
        const int b = n / Tn, t = n % Tn;
        float* rp = res + b*(Dn*Tn) + t;
        const float* ep = emb + bk*Dn;
        #pragma unroll
        for (int d = 0; d < Dn; ++d) {
            float rv = rp[d*Tn];
            float q  = ep[d];
            float diff = rv - q;                  // loss uses raw q
            lsum = fmaf(diff, diff, lsum);
            float qst = rv + (q - rv);            // straight-through, fp32-faithful
            rp[d*Tn] = rv - qst;
        }
    }
    red[tid] = lsum;
    __syncthreads();
    for (int s2 = 128; s2 > 0; s2 >>= 1) {
        if (tid < s2) red[tid] += red[tid + s2];
        __syncthreads();
    }
    if (tid == 0) atomicAdd(loss_acc, red[0]);
}

// ---------- quantized_total = x - residual_final (fp32 out) ----------
__global__ void vq_qt(const float* __restrict__ x, const float* __restrict__ res,
                      float* __restrict__ out)
{
    int j = blockIdx.x * 256 + threadIdx.x;   // float4 units: 768000
    if (j < (Nn*Dn)/4) {
        float4 xv = ((const float4*)x)[j];
        float4 rv = ((const float4*)res)[j];
        float4 o;
        o.x = xv.x - rv.x;
        o.y = xv.y - rv.y;
        o.z = xv.z - rv.z;
        o.w = xv.w - rv.w;
        ((float4*)out)[j] = o;
    }
}

// ---------- scalars: (commit+codebook)/NCB and utilization (fp32 out) ----------
__global__ void vq_scalars(const float* __restrict__ used, const float* __restrict__ loss_acc,
                           float* __restrict__ out)
{
    __shared__ float red[256];
    float s = 0.f;
    for (int j = threadIdx.x; j < NCB*Kn; j += 256) s += used[j];
    red[threadIdx.x] = s;
    __syncthreads();
    for (int st = 128; st > 0; st >>= 1) {
        if (threadIdx.x < st) red[threadIdx.x] += red[threadIdx.x + st];
        __syncthreads();
    }
    if (threadIdx.x == 0) {
        float sumsq = loss_acc[0];
        float total_loss = 2.0f * sumsq / (float)(Nn*Dn);  // sum over stages of commit+codebook
        out[OUT_SC_OFF + 0] = total_loss / (float)NCB;
        out[OUT_SC_OFF + 1] = red[0] / (float)(NCB*Kn);
    }
}

extern "C" void kernel_launch(void* const* d_in, const int* in_sizes, int n_in,
                              void* d_out, int out_size, void* d_ws, size_t ws_size,
                              hipStream_t stream)
{
    const float* x      = (const float*)d_in[0];
    const float* embeds = (const float*)d_in[1];
    float* out = (float*)d_out;
    char* ws = (char*)d_ws;

    float* res  = (float*)(ws + WS_RES);
    float* pval = (float*)(ws + WS_PVAL);
    int*   pidx = (int*)  (ws + WS_PIDX);
    float* se   = (float*)(ws + WS_SE);
    float* used = (float*)(ws + WS_USED);
    float* loss = (float*)(ws + WS_LOSS);

    // init: residual = x; used/loss = 0
    hipMemcpyAsync(res, x, (size_t)Nn*Dn*sizeof(float), hipMemcpyDeviceToDevice, stream);
    hipMemsetAsync(used, 0, (size_t)NCB*Kn*sizeof(float) + 16, stream);

    vq_se<<<(NCB*Kn + 255)/256, 256, 0, stream>>>(embeds, se);

    for (int s = 0; s < NCB; ++s) {
        const float* emb_s = embeds + (size_t)s*Kn*Dn;
        vq_dist<<<dim3(NTIL, KSPL), 256, 0, stream>>>(res, emb_s, se + s*Kn, pval, pidx);
        vq_comb<<<NTIL, 256, 0, stream>>>(res, emb_s, pval, pidx,
                                          out + OUT_IDX_OFF + s*Nn,
                                          used + s*Kn, loss);
    }

    vq_qt<<<((Nn*Dn)/4 + 255)/256, 256, 0, stream>>>(x, res, out + OUT_QT_OFF);
    vq_scalars<<<1, 256, 0, stream>>>(used, loss, out);
}

// Round 5
// 999.639 us; speedup vs baseline: 7.0789x; 1.2510x over previous
//
#include <hip/hip_runtime.h>
#include <hip/hip_bf16.h>
#include <math.h>

// Problem constants
#define Bn   16
#define Dn   64
#define Tn   3000
#define Nn   (Bn*Tn)          // 48000
#define NCB  8
#define Kn   1024
#define KTB  128              // codes per block (k-tile)
#define KSPL (Kn/KTB)         // 8 k-splits
#define NTB  64               // n per block (n-tile)
#define NBLK (Nn/NTB)         // 750 (exact)
#define NTIL ((Nn + 255)/256) // 188 (for comb/qt grids)
#define PSTR 48128            // padded partial stride (>= Nn, 128-aligned)

// LDS layout (bytes)
#define RSTRIDE 68            // floats per r-row  (64 + 4 pad; 272 B, 16B-aligned)
#define ESTRIDE 132           // floats per e-row  (128 + 4 pad; 528 B, 16B-aligned)
#define SM_R    0                       // float[64][RSTRIDE] = 17408 B
#define SM_E    17408                   // float[64][ESTRIDE] = 33792 B
#define SM_SE   (17408+33792)           // float[128] = 512 B
#define SM_SRP  (SM_SE+512)             // float[4][64] = 1024 B
#define SM_SR   (SM_SRP+1024)           // float[64] = 256 B
#define SM_TOT  (SM_SR+256)             // 52992 B -> 3 blocks/CU
#define SM_SCR  SM_E                    // float2[64][33] aliases e-tile (16896 B)

// Workspace byte offsets
#define WS_RES  0                              // float[3072000] residual
#define WS_PVAL 12288000                       // float[KSPL*PSTR]
#define WS_PIDX (WS_PVAL + KSPL*PSTR*4)        // int[KSPL*PSTR]
#define WS_SE   (WS_PIDX + KSPL*PSTR*4)        // float[NCB*Kn]
#define WS_USED (WS_SE + NCB*Kn*4)             // float[NCB*Kn]
#define WS_LOSS (WS_USED + NCB*Kn*4)           // float[1] (+pad)

// Output element offsets (fp32 elements)
#define OUT_QT_OFF  0
#define OUT_IDX_OFF 3072000
#define OUT_SC_OFF  3456000

// ---------- precompute ||e_k||^2 for all 8 codebooks ----------
__global__ void vq_se(const float* __restrict__ emb, float* __restrict__ se)
{
    int r = blockIdx.x * 256 + threadIdx.x;   // 0..8191
    if (r < NCB*Kn) {
        const float* p = emb + r*Dn;
        float a0=0.f, a1=0.f, a2=0.f, a3=0.f;
        #pragma unroll
        for (int d = 0; d < Dn; d += 4) {
            a0 = fmaf(p[d+0], p[d+0], a0);
            a1 = fmaf(p[d+1], p[d+1], a1);
            a2 = fmaf(p[d+2], p[d+2], a2);
            a3 = fmaf(p[d+3], p[d+3], a3);
        }
        se[r] = (a0+a1)+(a2+a3);
    }
}

// ---------- GEMM-tiled distance + per-(ntile,ktile) argmin ----------
// grid (NBLK, KSPL), block 256. Thread tile: m=8 n x kk=4 codes.
__global__ __launch_bounds__(256, 3)
void vq_dist(const float* __restrict__ res, const float* __restrict__ emb,
             const float* __restrict__ se,
             float* __restrict__ pval, int* __restrict__ pidx)
{
    __shared__ __align__(16) char smem[SM_TOT];
    float* lds_r  = (float*)(smem + SM_R);
    float* lds_e  = (float*)(smem + SM_E);
    float* selds  = (float*)(smem + SM_SE);
    float* srpart = (float*)(smem + SM_SRP);
    float* lds_sr = (float*)(smem + SM_SR);

    const int tid = threadIdx.x;
    const int n0 = blockIdx.x * NTB;
    const int kbase = blockIdx.y * KTB;

    // ---- stage r-tile transposed [d][n], plus ||r||^2 partials ----
    {
        const int nl = tid & 63;             // n-local 0..63
        const int dg = tid >> 6;             // d-group 0..3
        const int n = n0 + nl;
        const int b = n / Tn, t = n % Tn;
        const float* gp = res + b*(Dn*Tn) + t;
        float p = 0.f;
        #pragma unroll
        for (int j = 0; j < 16; ++j) {
            int d = dg*16 + j;
            float v = gp[d*Tn];
            lds_r[d*RSTRIDE + nl] = v;
            p = fmaf(v, v, p);
        }
        srpart[dg*64 + nl] = p;
    }
    // ---- stage e-tile transposed [d][k] ----
    {
        const float4* src = (const float4*)(emb + (size_t)kbase*Dn);
        #pragma unroll
        for (int j = 0; j < 8; ++j) {
            int f = tid + j*256;             // 0..2047 float4 units
            int k = f >> 4;                  // 0..127
            int d0 = (f & 15) * 4;
            float4 v = src[f];
            lds_e[(d0+0)*ESTRIDE + k] = v.x;
            lds_e[(d0+1)*ESTRIDE + k] = v.y;
            lds_e[(d0+2)*ESTRIDE + k] = v.z;
            lds_e[(d0+3)*ESTRIDE + k] = v.w;
        }
        if (tid < KTB) selds[tid] = se[kbase + tid];
    }
    __syncthreads();
    if (tid < 64) {
        float s = ((srpart[tid] + srpart[64+tid]) + (srpart[128+tid] + srpart[192+tid]));
        lds_sr[tid] = s;
    }

    // ---- dim-loop: acc[8][4] over 64 dims ----
    const int ty = tid & 7;        // n-group: rows ty*8 .. ty*8+7
    const int tx = tid >> 3;       // k-group: codes tx*4 .. tx*4+3
    float acc[8][4] = {};
    #pragma unroll 4
    for (int d = 0; d < Dn; ++d) {
        float4 ra = *(const float4*)&lds_r[d*RSTRIDE + ty*8];
        float4 rb = *(const float4*)&lds_r[d*RSTRIDE + ty*8 + 4];
        float4 ev = *(const float4*)&lds_e[d*ESTRIDE + tx*4];
        float rr[8] = { ra.x, ra.y, ra.z, ra.w, rb.x, rb.y, rb.z, rb.w };
        float ee[4] = { ev.x, ev.y, ev.z, ev.w };
        #pragma unroll
        for (int i = 0; i < 8; ++i)
            #pragma unroll
            for (int c = 0; c < 4; ++c)
                acc[i][c] = fmaf(rr[i], ee[c], acc[i][c]);
    }
    __syncthreads();               // dim-loop done everywhere; e-tile now dead

    // ---- epilogue: per-thread argmin over its 4 codes, per n ----
    float2* scr = (float2*)(smem + SM_SCR);   // [64][33]
    #pragma unroll
    for (int i = 0; i < 8; ++i) {
        int nl = ty*8 + i;
        float sr = lds_sr[nl];
        float best = INFINITY; int bk = 0;
        #pragma unroll
        for (int c = 0; c < 4; ++c) {
            int kl = tx*4 + c;
            float d2 = (sr - 2.0f*acc[i][c]) + selds[kl];   // ref rounding order
            if (d2 < best) { best = d2; bk = kbase + kl; }  // strict <, k ascending
        }
        float2 w; w.x = best; w.y = __int_as_float(bk);
        scr[nl*33 + tx] = w;
    }
    __syncthreads();
    if (tid < 64) {
        float best = INFINITY; int bk = 0;
        #pragma unroll
        for (int x = 0; x < 32; ++x) {        // tx ascending = k ascending
            float2 w = scr[tid*33 + x];
            if (w.x < best) { best = w.x; bk = __float_as_int(w.y); }
        }
        pval[blockIdx.y*PSTR + n0 + tid] = best;
        pidx[blockIdx.y*PSTR + n0 + tid] = bk;
    }
}

// ---------- combine partials + residual update + loss/util ----------
__global__ void vq_comb(float* __restrict__ res, const float* __restrict__ emb,
                        const float* __restrict__ pval, const int* __restrict__ pidx,
                        float* __restrict__ out_idx,             // + stage*Nn (fp32)
                        float* __restrict__ used,                // + stage*Kn
                        float* __restrict__ loss_acc)
{
    __shared__ float red[256];
    const int tid = threadIdx.x;
    const int n = blockIdx.x * 256 + tid;
    float lsum = 0.f;
    if (n < Nn) {
        float best = INFINITY; int bk = 0;
        #pragma unroll
        for (int c = 0; c < KSPL; ++c) {          // ascending chunks: first-occurrence
            float v = pval[c*PSTR + n];
            int   k = pidx[c*PSTR + n];
            if (v < best) { best = v; bk = k; }
        }
        bk &= (Kn - 1);                           // provably no-op OOB guard
        out_idx[n] = (float)bk;
        used[bk] = 1.0f;
        const int b = n / Tn, t = n % Tn;
        float* rp = res + b*(Dn*Tn) + t;
        const float* ep = emb + bk*Dn;
        #pragma unroll
        for (int d = 0; d < Dn; ++d) {
            float rv = rp[d*Tn];
            float q  = ep[d];
            float diff = rv - q;                  // loss uses raw q
            lsum = fmaf(diff, diff, lsum);
            float qst = rv + (q - rv);            // straight-through, fp32-faithful
            rp[d*Tn] = rv - qst;
        }
    }
    red[tid] = lsum;
    __syncthreads();
    for (int s2 = 128; s2 > 0; s2 >>= 1) {
        if (tid < s2) red[tid] += red[tid + s2];
        __syncthreads();
    }
    if (tid == 0) atomicAdd(loss_acc, red[0]);
}

// ---------- quantized_total = x - residual_final (fp32 out) ----------
__global__ void vq_qt(const float* __restrict__ x, const float* __restrict__ res,
                      float* __restrict__ out)
{
    int j = blockIdx.x * 256 + threadIdx.x;   // float4 units: 768000
    if (j < (Nn*Dn)/4) {
        float4 xv = ((const float4*)x)[j];
        float4 rv = ((const float4*)res)[j];
        float4 o;
        o.x = xv.x - rv.x;
        o.y = xv.y - rv.y;
        o.z = xv.z - rv.z;
        o.w = xv.w - rv.w;
        ((float4*)out)[j] = o;
    }
}

// ---------- scalars: (commit+codebook)/NCB and utilization (fp32 out) ----------
__global__ void vq_scalars(const float* __restrict__ used, const float* __restrict__ loss_acc,
                           float* __restrict__ out)
{
    __shared__ float red[256];
    float s = 0.f;
    for (int j = threadIdx.x; j < NCB*Kn; j += 256) s += used[j];
    red[threadIdx.x] = s;
    __syncthreads();
    for (int st = 128; st > 0; st >>= 1) {
        if (threadIdx.x < st) red[threadIdx.x] += red[threadIdx.x + st];
        __syncthreads();
    }
    if (threadIdx.x == 0) {
        float sumsq = loss_acc[0];
        float total_loss = 2.0f * sumsq / (float)(Nn*Dn);  // sum over stages of commit+codebook
        out[OUT_SC_OFF + 0] = total_loss / (float)NCB;
        out[OUT_SC_OFF + 1] = red[0] / (float)(NCB*Kn);
    }
}

extern "C" void kernel_launch(void* const* d_in, const int* in_sizes, int n_in,
                              void* d_out, int out_size, void* d_ws, size_t ws_size,
                              hipStream_t stream)
{
    const float* x      = (const float*)d_in[0];
    const float* embeds = (const float*)d_in[1];
    float* out = (float*)d_out;
    char* ws = (char*)d_ws;

    float* res  = (float*)(ws + WS_RES);
    float* pval = (float*)(ws + WS_PVAL);
    int*   pidx = (int*)  (ws + WS_PIDX);
    float* se   = (float*)(ws + WS_SE);
    float* used = (float*)(ws + WS_USED);
    float* loss = (float*)(ws + WS_LOSS);

    // init: residual = x; used/loss = 0
    hipMemcpyAsync(res, x, (size_t)Nn*Dn*sizeof(float), hipMemcpyDeviceToDevice, stream);
    hipMemsetAsync(used, 0, (size_t)NCB*Kn*sizeof(float) + 16, stream);

    vq_se<<<(NCB*Kn + 255)/256, 256, 0, stream>>>(embeds, se);

    for (int s = 0; s < NCB; ++s) {
        const float* emb_s = embeds + (size_t)s*Kn*Dn;
        vq_dist<<<dim3(NBLK, KSPL), 256, 0, stream>>>(res, emb_s, se + s*Kn, pval, pidx);
        vq_comb<<<NTIL, 256, 0, stream>>>(res, emb_s, pval, pidx,
                                          out + OUT_IDX_OFF + s*Nn,
                                          used + s*Kn, loss);
    }

    vq_qt<<<((Nn*Dn)/4 + 255)/256, 256, 0, stream>>>(x, res, out + OUT_QT_OFF);
    vq_scalars<<<1, 256, 0, stream>>>(used, loss, out);
}

// Round 6
// 832.210 us; speedup vs baseline: 8.5031x; 1.2012x over previous
//
#include <hip/hip_runtime.h>
#include <hip/hip_bf16.h>
#include <math.h>

// Problem constants
#define Bn   16
#define Dn   64
#define Tn   3000
#define Nn   (Bn*Tn)          // 48000
#define NCB  8
#define Kn   1024
#define KTB  128              // codes per block (k-tile)
#define KSPL (Kn/KTB)         // 8 k-splits
#define NTB  128              // n per block (n-tile)
#define NBLK (Nn/NTB)         // 375 (exact)
#define NTIL ((Nn + 255)/256) // 188 (for comb/qt grids)
#define PSTR 48128            // padded partial stride (>= Nn, 128-aligned)

// LDS layout (bytes). Both tiles stored [d][x] with bank-aware permutation.
#define SM_R    0                       // float[64][128] = 32768 B (perm G on n-groups)
#define SM_E    32768                   // float[64][128] = 32768 B (perm G + rotate d>>2)
#define SM_SE   65536                   // float[128] = 512 B
#define SM_SRP  66048                   // float[2][128] = 1024 B
#define SM_SR   67072                   // float[128] = 512 B
#define SM_TOT  67584                   // -> 2 blocks/CU
#define SM_SCR  SM_E                    // float2[128][5] aliases e-tile (5120 B)

// Workspace byte offsets
#define WS_RES  0                              // float[3072000] residual
#define WS_PVAL 12288000                       // float[KSPL*PSTR]
#define WS_PIDX (WS_PVAL + KSPL*PSTR*4)        // int[KSPL*PSTR]
#define WS_SE   (WS_PIDX + KSPL*PSTR*4)        // float[NCB*Kn]
#define WS_USED (WS_SE + NCB*Kn*4)             // float[NCB*Kn]
#define WS_LOSS (WS_USED + NCB*Kn*4)           // float[1] (+pad)

// Output element offsets (fp32 elements)
#define OUT_QT_OFF  0
#define OUT_IDX_OFF 3072000
#define OUT_SC_OFF  3456000

// group-interleave permutation: g in 0..31 -> (g&1)*16 + g/2
__device__ __forceinline__ int permG(int g) { return ((g & 1) << 4) | (g >> 1); }

// ---------- precompute ||e_k||^2 for all 8 codebooks ----------
__global__ void vq_se(const float* __restrict__ emb, float* __restrict__ se)
{
    int r = blockIdx.x * 256 + threadIdx.x;   // 0..8191
    if (r < NCB*Kn) {
        const float* p = emb + r*Dn;
        float a0=0.f, a1=0.f, a2=0.f, a3=0.f;
        #pragma unroll
        for (int d = 0; d < Dn; d += 4) {
            a0 = fmaf(p[d+0], p[d+0], a0);
            a1 = fmaf(p[d+1], p[d+1], a1);
            a2 = fmaf(p[d+2], p[d+2], a2);
            a3 = fmaf(p[d+3], p[d+3], a3);
        }
        se[r] = (a0+a1)+(a2+a3);
    }
}

// ---------- GEMM-tiled distance + per-(ntile,ktile) argmin ----------
// grid (NBLK, KSPL), block 256. Thread tile: 8 n x 8 codes (acc[8][8]).
__global__ __launch_bounds__(256, 2)
void vq_dist(const float* __restrict__ res, const float* __restrict__ emb,
             const float* __restrict__ se,
             float* __restrict__ pval, int* __restrict__ pidx)
{
    __shared__ __align__(16) char smem[SM_TOT];
    float* lds_r  = (float*)(smem + SM_R);
    float* lds_e  = (float*)(smem + SM_E);
    float* selds  = (float*)(smem + SM_SE);
    float* srpart = (float*)(smem + SM_SRP);
    float* lds_sr = (float*)(smem + SM_SR);

    const int tid = threadIdx.x;
    const int n0 = blockIdx.x * NTB;
    const int kbase = blockIdx.y * KTB;

    // ---- stage r-tile [d][n] with perm G on n-groups; ||r||^2 partials ----
    {
        const int nl = tid & 127;            // n-local 0..127
        const int dg = tid >> 7;             // 0..1 (d-halves)
        const int n = n0 + nl;
        const int b = n / Tn, t = n % Tn;
        const float* gp = res + b*(Dn*Tn) + t;
        const int wbase = permG(nl >> 2)*4 + (nl & 3);
        float p = 0.f;
        #pragma unroll
        for (int j = 0; j < 32; ++j) {
            int d = dg*32 + j;
            float v = gp[d*Tn];
            lds_r[d*128 + wbase] = v;
            p = fmaf(v, v, p);
        }
        srpart[dg*128 + nl] = p;
    }
    // ---- stage e-tile [d][k] with perm G + rotate by (d>>2) ----
    {
        const float4* src = (const float4*)(emb + (size_t)kbase*Dn);
        #pragma unroll
        for (int j = 0; j < 8; ++j) {
            int f = tid + j*256;             // 0..2047 float4 units
            int k = f >> 4;                  // 0..127
            int d0 = (f & 15) * 4;
            int m  = f & 15;                 // (d0+i)>>2 for i in 0..3
            int pg = permG(k >> 2);
            float4 v = src[f];
            int p0 = ((pg + m) & 31)*4 + (k & 3);
            lds_e[(d0+0)*128 + p0] = v.x;
            lds_e[(d0+1)*128 + p0] = v.y;
            lds_e[(d0+2)*128 + p0] = v.z;
            lds_e[(d0+3)*128 + p0] = v.w;
        }
        if (tid < KTB) selds[tid] = se[kbase + tid];
    }
    __syncthreads();
    if (tid < 128) lds_sr[tid] = srpart[tid] + srpart[128 + tid];

    // ---- dim loop: acc[8][8] over 64 dims ----
    const int ty = tid & 15;       // n-group: rows ty*8 .. ty*8+7
    const int tx = tid >> 4;       // k-group: codes tx*8 .. tx*8+7
    const char* rbase = smem + SM_R + ty*16;
    float acc[8][8] = {};
    for (int dm = 0; dm < 16; ++dm) {        // dm = d>>2
        const char* eA = smem + SM_E + dm*2048 + ((((tx + dm) & 31)) << 4);
        const char* eB = smem + SM_E + dm*2048 + ((((tx + dm + 16) & 31)) << 4);
        const char* rB = rbase + dm*2048;
        #pragma unroll
        for (int dd = 0; dd < 4; ++dd) {
            const int off = dd*512;
            float4 ra = *(const float4*)(rB + off);
            float4 rb = *(const float4*)(rB + off + 256);
            float4 ea = *(const float4*)(eA + off);
            float4 eb = *(const float4*)(eB + off);
            float rr[8] = { ra.x, ra.y, ra.z, ra.w, rb.x, rb.y, rb.z, rb.w };
            float ee[8] = { ea.x, ea.y, ea.z, ea.w, eb.x, eb.y, eb.z, eb.w };
            #pragma unroll
            for (int i = 0; i < 8; ++i)
                #pragma unroll
                for (int c = 0; c < 8; ++c)
                    acc[i][c] = fmaf(rr[i], ee[c], acc[i][c]);
        }
    }
    __syncthreads();               // dim loop done everywhere; e-tile now dead

    // ---- epilogue: per-row argmin over 8 codes, then cross-lane (tx) reduce ----
    float2* scr = (float2*)(smem + SM_SCR);   // [128][5]
    const int w = tid >> 6;                   // wave id 0..3 (covers tx = 4w..4w+3)
    #pragma unroll
    for (int i = 0; i < 8; ++i) {
        const int row = ty*8 + i;
        const float sr = lds_sr[row];
        float best = INFINITY; int bk = 0;
        #pragma unroll
        for (int c = 0; c < 8; ++c) {
            int kl = tx*8 + c;
            float d2 = (sr - 2.0f*acc[i][c]) + selds[kl];   // ref rounding order
            if (d2 < best) { best = d2; bk = kbase + kl; }  // strict <, k ascending
        }
        // reduce across tx within wave (lanes tid^16, tid^32 share ty)
        #pragma unroll
        for (int mask = 16; mask <= 32; mask <<= 1) {
            float ov = __shfl_xor(best, mask, 64);
            int   ok = __shfl_xor(bk,   mask, 64);
            if (ov < best || (ov == best && ok < bk)) { best = ov; bk = ok; }
        }
        if ((tid & 48) == 0) {                 // one lane per (row, wave)
            float2 v; v.x = best; v.y = __int_as_float(bk);
            scr[row*5 + w] = v;
        }
    }
    __syncthreads();
    if (tid < 128) {
        float best = INFINITY; int bk = 0;
        #pragma unroll
        for (int x = 0; x < 4; ++x) {          // w ascending = k ascending
            float2 v = scr[tid*5 + x];
            int   ok = __float_as_int(v.y);
            if (v.x < best || (v.x == best && ok < bk)) { best = v.x; bk = ok; }
        }
        pval[blockIdx.y*PSTR + n0 + tid] = best;
        pidx[blockIdx.y*PSTR + n0 + tid] = bk;
    }
}

// ---------- combine partials + residual update + loss/util ----------
__global__ void vq_comb(float* __restrict__ res, const float* __restrict__ emb,
                        const float* __restrict__ pval, const int* __restrict__ pidx,
                        float* __restrict__ out_idx,             // + stage*Nn (fp32)
                        float* __restrict__ used,                // + stage*Kn
                        float* __restrict__ loss_acc)
{
    __shared__ float red[256];
    const int tid = threadIdx.x;
    const int n = blockIdx.x * 256 + tid;
    float lsum = 0.f;
    if (n < Nn) {
        float best = INFINITY; int bk = 0;
        #pragma unroll
        for (int c = 0; c < KSPL; ++c) {          // ascending chunks: first-occurrence
            float v = pval[c*PSTR + n];
            int   k = pidx[c*PSTR + n];
            if (v < best) { best = v; bk = k; }
        }
        bk &= (Kn - 1);                           // provably no-op OOB guard
        out_idx[n] = (float)bk;
        used[bk] = 1.0f;
        const int b = n / Tn, t = n % Tn;
        float* rp = res + b*(Dn*Tn) + t;
        const float* ep = emb + bk*Dn;
        #pragma unroll
        for (int d = 0; d < Dn; ++d) {
            float rv = rp[d*Tn];
            float q  = ep[d];
            float diff = rv - q;                  // loss uses raw q
            lsum = fmaf(diff, diff, lsum);
            float qst = rv + (q - rv);            // straight-through, fp32-faithful
            rp[d*Tn] = rv - qst;
        }
    }
    red[tid] = lsum;
    __syncthreads();
    for (int s2 = 128; s2 > 0; s2 >>= 1) {
        if (tid < s2) red[tid] += red[tid + s2];
        __syncthreads();
    }
    if (tid == 0) atomicAdd(loss_acc, red[0]);
}

// ---------- quantized_total = x - residual_final (fp32 out) ----------
__global__ void vq_qt(const float* __restrict__ x, const float* __restrict__ res,
                      float* __restrict__ out)
{
    int j = blockIdx.x * 256 + threadIdx.x;   // float4 units: 768000
    if (j < (Nn*Dn)/4) {
        float4 xv = ((const float4*)x)[j];
        float4 rv = ((const float4*)res)[j];
        float4 o;
        o.x = xv.x - rv.x;
        o.y = xv.y - rv.y;
        o.z = xv.z - rv.z;
        o.w = xv.w - rv.w;
        ((float4*)out)[j] = o;
    }
}

// ---------- scalars: (commit+codebook)/NCB and utilization (fp32 out) ----------
__global__ void vq_scalars(const float* __restrict__ used, const float* __restrict__ loss_acc,
                           float* __restrict__ out)
{
    __shared__ float red[256];
    float s = 0.f;
    for (int j = threadIdx.x; j < NCB*Kn; j += 256) s += used[j];
    red[threadIdx.x] = s;
    __syncthreads();
    for (int st = 128; st > 0; st >>= 1) {
        if (threadIdx.x < st) red[threadIdx.x] += red[threadIdx.x + st];
        __syncthreads();
    }
    if (threadIdx.x == 0) {
        float sumsq = loss_acc[0];
        float total_loss = 2.0f * sumsq / (float)(Nn*Dn);  // sum over stages of commit+codebook
        out[OUT_SC_OFF + 0] = total_loss / (float)NCB;
        out[OUT_SC_OFF + 1] = red[0] / (float)(NCB*Kn);
    }
}

extern "C" void kernel_launch(void* const* d_in, const int* in_sizes, int n_in,
                              void* d_out, int out_size, void* d_ws, size_t ws_size,
                              hipStream_t stream)
{
    const float* x      = (const float*)d_in[0];
    const float* embeds = (const float*)d_in[1];
    float* out = (float*)d_out;
    char* ws = (char*)d_ws;

    float* res  = (float*)(ws + WS_RES);
    float* pval = (float*)(ws + WS_PVAL);
    int*   pidx = (int*)  (ws + WS_PIDX);
    float* se   = (float*)(ws + WS_SE);
    float* used = (float*)(ws + WS_USED);
    float* loss = (float*)(ws + WS_LOSS);

    // init: residual = x; used/loss = 0
    hipMemcpyAsync(res, x, (size_t)Nn*Dn*sizeof(float), hipMemcpyDeviceToDevice, stream);
    hipMemsetAsync(used, 0, (size_t)NCB*Kn*sizeof(float) + 16, stream);

    vq_se<<<(NCB*Kn + 255)/256, 256, 0, stream>>>(embeds, se);

    for (int s = 0; s < NCB; ++s) {
        const float* emb_s = embeds + (size_t)s*Kn*Dn;
        vq_dist<<<dim3(NBLK, KSPL), 256, 0, stream>>>(res, emb_s, se + s*Kn, pval, pidx);
        vq_comb<<<NTIL, 256, 0, stream>>>(res, emb_s, pval, pidx,
                                          out + OUT_IDX_OFF + s*Nn,
                                          used + s*Kn, loss);
    }

    vq_qt<<<((Nn*Dn)/4 + 255)/256, 256, 0, stream>>>(x, res, out + OUT_QT_OFF);
    vq_scalars<<<1, 256, 0, stream>>>(used, loss, out);
}